// Round 1
// baseline (212.356 us; speedup 1.0000x reference)
//
#include <hip/hip_runtime.h>
#include <stdint.h>

typedef __attribute__((ext_vector_type(4))) float f32x4;
typedef __attribute__((ext_vector_type(8))) __bf16 bf16x8;
typedef __attribute__((ext_vector_type(8))) unsigned short u16x8;

__device__ __forceinline__ unsigned short f2b(float f) {
  unsigned u = __float_as_uint(f);
  u += 0x7FFFu + ((u >> 16) & 1u);   // RNE
  return (unsigned short)(u >> 16);
}

__device__ __forceinline__ void gload_lds16(const void* g, void* l) {
  typedef __attribute__((address_space(1))) void GV1;
  typedef __attribute__((address_space(3))) void LV3;
  __builtin_amdgcn_global_load_lds((GV1*)(void*)g, (LV3*)l, 16, 0, 0);
}

// ---------------- conversion kernels ----------------
__global__ __launch_bounds__(256) void convert_f32_bf16(const float* __restrict__ in,
                                                        unsigned short* __restrict__ out, int n) {
  int i = (blockIdx.x * 256 + threadIdx.x) * 8;
  if (i >= n) return;
  float4 a = *(const float4*)(in + i);
  float4 b = *(const float4*)(in + i + 4);
  u16x8 r;
  r[0] = f2b(a.x); r[1] = f2b(a.y); r[2] = f2b(a.z); r[3] = f2b(a.w);
  r[4] = f2b(b.x); r[5] = f2b(b.y); r[6] = f2b(b.z); r[7] = f2b(b.w);
  *(u16x8*)(out + i) = r;
}

// W [K][N] f32 -> Wt [N][K] bf16
__global__ __launch_bounds__(256) void transpose_f32_bf16(const float* __restrict__ W,
                                                          unsigned short* __restrict__ Wt,
                                                          int K, int N) {
  __shared__ unsigned short tile[32][33];
  int n0 = blockIdx.x * 32, k0 = blockIdx.y * 32;
  int tx = threadIdx.x, ty = threadIdx.y;  // 32 x 8
  #pragma unroll
  for (int j = 0; j < 32; j += 8)
    tile[ty + j][tx] = f2b(W[(size_t)(k0 + ty + j) * N + n0 + tx]);
  __syncthreads();
  #pragma unroll
  for (int j = 0; j < 32; j += 8)
    Wt[(size_t)(n0 + ty + j) * K + k0 + tx] = tile[tx][ty + j];
}

// ---------------- GEMM: C[M][N] = A[M][K] * Bt[N][K]^T + bias ----------------
// m97 structure: 128x128 tile, BK=64, 4 waves (2x2), 4x4 16x16x32 frags/wave,
// global_load_lds width=16 staging, single-buffered 2-barrier loop.
template <bool OUT_BF16>
__global__ __launch_bounds__(256) void gemm_bt(const unsigned short* __restrict__ A,
                                               const unsigned short* __restrict__ Bt,
                                               const float* __restrict__ bias,
                                               void* __restrict__ Cout,
                                               int M, int N, int K) {
  __shared__ unsigned short As[128 * 64];
  __shared__ unsigned short Bs[128 * 64];
  const int m0 = blockIdx.x * 128, n0 = blockIdx.y * 128;
  const int tid = threadIdx.x;
  const int w = tid >> 6, l = tid & 63;
  const int wm = w >> 1, wn = w & 1;
  const int c = l & 15, g = l >> 4;
  f32x4 acc[4][4] = {};
  for (int k0 = 0; k0 < K; k0 += 64) {
    #pragma unroll
    for (int i = 0; i < 4; ++i) {
      int rb = w * 32 + i * 8;  // wave-uniform LDS base, lane covers (row=rb+l/8, chunk=l%8)
      gload_lds16(A + (size_t)(m0 + rb + (l >> 3)) * K + k0 + (l & 7) * 8, &As[rb * 64]);
      gload_lds16(Bt + (size_t)(n0 + rb + (l >> 3)) * K + k0 + (l & 7) * 8, &Bs[rb * 64]);
    }
    __syncthreads();
    #pragma unroll
    for (int ks = 0; ks < 2; ++ks) {
      bf16x8 af[4], bf[4];
      #pragma unroll
      for (int mi = 0; mi < 4; ++mi)
        af[mi] = *(const bf16x8*)&As[(wm * 64 + mi * 16 + c) * 64 + ks * 32 + g * 8];
      #pragma unroll
      for (int ni = 0; ni < 4; ++ni)
        bf[ni] = *(const bf16x8*)&Bs[(wn * 64 + ni * 16 + c) * 64 + ks * 32 + g * 8];
      #pragma unroll
      for (int mi = 0; mi < 4; ++mi)
        #pragma unroll
        for (int ni = 0; ni < 4; ++ni)
          acc[mi][ni] = __builtin_amdgcn_mfma_f32_16x16x32_bf16(af[mi], bf[ni], acc[mi][ni], 0, 0, 0);
    }
    __syncthreads();
  }
  #pragma unroll
  for (int mi = 0; mi < 4; ++mi) {
    #pragma unroll
    for (int ni = 0; ni < 4; ++ni) {
      int colg = n0 + wn * 64 + ni * 16 + c;
      float bv = bias[colg];
      #pragma unroll
      for (int r = 0; r < 4; ++r) {
        int rowg = m0 + wm * 64 + mi * 16 + 4 * g + r;  // D: row=4*(l>>4)+r, col=l&15
        float v = acc[mi][ni][r] + bv;
        if (OUT_BF16)
          ((unsigned short*)Cout)[(size_t)rowg * N + colg] = f2b(v);
        else
          ((float*)Cout)[(size_t)rowg * N + colg] = v;
      }
    }
  }
}

// ---------------- causal flash attention ----------------
// qkv [4096][3072] bf16 (cols: 0..1023=Q, 1024..2047=K, 2048..3071=V; within: h*64+d)
// out [4096][1024] bf16 (t-major, col=h*64+d)
// Block: (q-tile of 128) x (b,h). 4 waves x 32 q-rows. KV tiles of 64.
__global__ __launch_bounds__(256) void attn_kernel(const unsigned short* __restrict__ qkv,
                                                   unsigned short* __restrict__ out) {
  __shared__ unsigned short K_lds[64 * 64];        // [kv][d], XOR-swizzled rows
  __shared__ unsigned short V_lds[64 * 64];        // V^T [d][kv], XOR-swizzled rows
  __shared__ unsigned short P_lds[4 * 32 * 64];    // per-wave [32 q][64 kv], swizzled
  const int qt = blockIdx.x, bh = blockIdx.y;
  const int b = bh >> 4, h = bh & 15;
  const int tid = threadIdx.x, w = tid >> 6, l = tid & 63;
  const int c = l & 15, g = l >> 4;
  const int q0 = qt * 128;
  const int q0w = q0 + w * 32;
  const size_t row0 = (size_t)b * 2048;

  // Q fragments in registers: A-frag m=c(+mi*16), k=d=ks*32+8g+e
  bf16x8 qf[2][2];
  #pragma unroll
  for (int mi = 0; mi < 2; ++mi)
    #pragma unroll
    for (int ks = 0; ks < 2; ++ks)
      qf[mi][ks] = *(const bf16x8*)(qkv + (row0 + q0w + mi * 16 + c) * 3072 + h * 64 + ks * 32 + g * 8);

  f32x4 acc[2][4] = {};
  float mstate[2][4], lstate[2][4];
  #pragma unroll
  for (int mi = 0; mi < 2; ++mi)
    #pragma unroll
    for (int r = 0; r < 4; ++r) { mstate[mi][r] = -1e30f; lstate[mi][r] = 0.f; }

  char* Kb = (char*)K_lds;
  char* Vb = (char*)V_lds;
  char* Pb = (char*)&P_lds[w * 32 * 64];

  const int kv_end = q0 + 128;
  for (int kv0 = 0; kv0 < kv_end; kv0 += 64) {
    // ---- stage K via global_load_lds; swizzle by pre-permuting the SOURCE chunk (m173)
    #pragma unroll
    for (int i = 0; i < 2; ++i) {
      int rb = w * 16 + i * 8;
      int row = rb + (l >> 3);
      int ch = (l & 7) ^ (row & 7);
      gload_lds16(qkv + (row0 + kv0 + row) * 3072 + 1024 + h * 64 + ch * 8, &K_lds[rb * 64]);
    }
    // ---- stage V transposed (reg-staged, paired kv -> b32 writes, swizzled)
    {
      int p = tid & 31, cb = tid >> 5;
      size_t tr = row0 + kv0 + 2 * p;
      u16x8 v0 = *(const u16x8*)(qkv + tr * 3072 + 2048 + h * 64 + cb * 8);
      u16x8 v1 = *(const u16x8*)(qkv + (tr + 1) * 3072 + 2048 + h * 64 + cb * 8);
      #pragma unroll
      for (int j = 0; j < 8; ++j) {
        int d = cb * 8 + j;
        int off = d * 128 + ((4 * p) ^ ((d & 7) << 4));
        *(unsigned int*)(Vb + off) = (unsigned int)v0[j] | ((unsigned int)v1[j] << 16);
      }
    }
    __syncthreads();
    if (kv0 <= q0w + 31) {  // wave-uniform: skip fully-masked tiles
      // ---- S = Q K^T
      f32x4 s[2][4] = {};
      #pragma unroll
      for (int ks = 0; ks < 2; ++ks) {
        bf16x8 kf[4];
        #pragma unroll
        for (int nk = 0; nk < 4; ++nk) {
          int row = nk * 16 + c;
          kf[nk] = *(const bf16x8*)(Kb + row * 128 + ((ks * 64 + g * 16) ^ ((row & 7) << 4)));
        }
        #pragma unroll
        for (int mi = 0; mi < 2; ++mi)
          #pragma unroll
          for (int nk = 0; nk < 4; ++nk)
            s[mi][nk] = __builtin_amdgcn_mfma_f32_16x16x32_bf16(qf[mi][ks], kf[nk], s[mi][nk], 0, 0, 0);
      }
      // ---- scale + causal mask (D layout: row=4g+r(+mi*16), col=c(+nk*16))
      #pragma unroll
      for (int mi = 0; mi < 2; ++mi)
        #pragma unroll
        for (int nk = 0; nk < 4; ++nk)
          #pragma unroll
          for (int r = 0; r < 4; ++r) {
            float v = s[mi][nk][r] * 0.125f;
            int rowg = q0w + mi * 16 + 4 * g + r;
            int colg = kv0 + nk * 16 + c;
            s[mi][nk][r] = (colg > rowg) ? -1e30f : v;
          }
      // ---- online softmax (rows live in 16-lane groups -> 4x shfl_xor)
      #pragma unroll
      for (int mi = 0; mi < 2; ++mi)
        #pragma unroll
        for (int r = 0; r < 4; ++r) {
          float mx = fmaxf(fmaxf(s[mi][0][r], s[mi][1][r]), fmaxf(s[mi][2][r], s[mi][3][r]));
          mx = fmaxf(mx, __shfl_xor(mx, 1));
          mx = fmaxf(mx, __shfl_xor(mx, 2));
          mx = fmaxf(mx, __shfl_xor(mx, 4));
          mx = fmaxf(mx, __shfl_xor(mx, 8));
          float mold = mstate[mi][r];
          float mnew = fmaxf(mold, mx);
          float alpha = __expf(mold - mnew);
          mstate[mi][r] = mnew;
          float rs = 0.f;
          #pragma unroll
          for (int nk = 0; nk < 4; ++nk) {
            float p = __expf(s[mi][nk][r] - mnew);
            s[mi][nk][r] = p;
            rs += p;
          }
          rs += __shfl_xor(rs, 1);
          rs += __shfl_xor(rs, 2);
          rs += __shfl_xor(rs, 4);
          rs += __shfl_xor(rs, 8);
          lstate[mi][r] = lstate[mi][r] * alpha + rs;
          #pragma unroll
          for (int nd = 0; nd < 4; ++nd) acc[mi][nd][r] *= alpha;
        }
      // ---- P -> LDS (bf16, swizzled)
      #pragma unroll
      for (int mi = 0; mi < 2; ++mi)
        #pragma unroll
        for (int nk = 0; nk < 4; ++nk)
          #pragma unroll
          for (int r = 0; r < 4; ++r) {
            int row = mi * 16 + 4 * g + r;
            int off = row * 128 + (((nk * 16 + c) * 2) ^ ((row & 7) << 4));
            *(unsigned short*)(Pb + off) = f2b(s[mi][nk][r]);
          }
      // ---- O += P V
      #pragma unroll
      for (int ks = 0; ks < 2; ++ks) {
        bf16x8 pf[2], vf[4];
        #pragma unroll
        for (int mi = 0; mi < 2; ++mi) {
          int row = mi * 16 + c;
          pf[mi] = *(const bf16x8*)(Pb + row * 128 + ((ks * 64 + g * 16) ^ ((row & 7) << 4)));
        }
        #pragma unroll
        for (int nd = 0; nd < 4; ++nd) {
          int row = nd * 16 + c;
          vf[nd] = *(const bf16x8*)(Vb + row * 128 + ((ks * 64 + g * 16) ^ ((row & 7) << 4)));
        }
        #pragma unroll
        for (int mi = 0; mi < 2; ++mi)
          #pragma unroll
          for (int nd = 0; nd < 4; ++nd)
            acc[mi][nd] = __builtin_amdgcn_mfma_f32_16x16x32_bf16(pf[mi], vf[nd], acc[mi][nd], 0, 0, 0);
      }
    }
    __syncthreads();
  }
  // ---- epilogue: O /= l, write bf16 [t][h*64+d]
  #pragma unroll
  for (int mi = 0; mi < 2; ++mi)
    #pragma unroll
    for (int r = 0; r < 4; ++r) {
      float rinv = 1.0f / lstate[mi][r];
      size_t t = row0 + q0w + mi * 16 + 4 * g + r;
      #pragma unroll
      for (int nd = 0; nd < 4; ++nd)
        out[t * 1024 + h * 64 + nd * 16 + c] = f2b(acc[mi][nd][r] * rinv);
    }
}

// ---------------- launch ----------------
extern "C" void kernel_launch(void* const* d_in, const int* in_sizes, int n_in,
                              void* d_out, int out_size, void* d_ws, size_t ws_size,
                              hipStream_t stream) {
  const float* x      = (const float*)d_in[0];
  const float* W_attn = (const float*)d_in[1];
  const float* b_attn = (const float*)d_in[2];
  const float* W_proj = (const float*)d_in[3];
  const float* b_proj = (const float*)d_in[4];
  float* out = (float*)d_out;

  char* ws = (char*)d_ws;
  unsigned short* x_bf     = (unsigned short*)(ws + 0);           //  8 MB [4096][1024]
  unsigned short* Wattn_t  = (unsigned short*)(ws + 8388608);     //  6 MB [3072][1024]
  unsigned short* Wproj_t  = (unsigned short*)(ws + 14680064);    //  2 MB [1024][1024]
  unsigned short* qkv      = (unsigned short*)(ws + 16777216);    // 24 MB [4096][3072]
  unsigned short* attn_out = (unsigned short*)(ws + 41943040);    //  8 MB [4096][1024]
  // total ws use: 48 MB

  convert_f32_bf16<<<2048, 256, 0, stream>>>(x, x_bf, 4194304);
  transpose_f32_bf16<<<dim3(96, 32), dim3(32, 8), 0, stream>>>(W_attn, Wattn_t, 1024, 3072);
  transpose_f32_bf16<<<dim3(32, 32), dim3(32, 8), 0, stream>>>(W_proj, Wproj_t, 1024, 1024);

  gemm_bt<true><<<dim3(32, 24), 256, 0, stream>>>(x_bf, Wattn_t, b_attn, qkv, 4096, 3072, 1024);
  attn_kernel<<<dim3(16, 32), 256, 0, stream>>>(qkv, attn_out);
  gemm_bt<false><<<dim3(32, 8), 256, 0, stream>>>(attn_out, Wproj_t, b_proj, out, 4096, 1024, 1024);
}

// Round 2
// 205.973 us; speedup vs baseline: 1.0310x; 1.0310x over previous
//
#include <hip/hip_runtime.h>
#include <stdint.h>

typedef __attribute__((ext_vector_type(4))) float f32x4;
typedef __attribute__((ext_vector_type(8))) __bf16 bf16x8;
typedef __attribute__((ext_vector_type(8))) unsigned short u16x8;

__device__ __forceinline__ unsigned short f2b(float f) {
  unsigned u = __float_as_uint(f);
  u += 0x7FFFu + ((u >> 16) & 1u);   // RNE
  return (unsigned short)(u >> 16);
}

__device__ __forceinline__ void gload_lds16(const void* g, void* l) {
  typedef __attribute__((address_space(1))) void GV1;
  typedef __attribute__((address_space(3))) void LV3;
  __builtin_amdgcn_global_load_lds((GV1*)(void*)g, (LV3*)l, 16, 0, 0);
}

// ---------------- conversion kernels ----------------
__global__ __launch_bounds__(256) void convert_f32_bf16(const float* __restrict__ in,
                                                        unsigned short* __restrict__ out, int n) {
  int i = (blockIdx.x * 256 + threadIdx.x) * 8;
  if (i >= n) return;
  float4 a = *(const float4*)(in + i);
  float4 b = *(const float4*)(in + i + 4);
  u16x8 r;
  r[0] = f2b(a.x); r[1] = f2b(a.y); r[2] = f2b(a.z); r[3] = f2b(a.w);
  r[4] = f2b(b.x); r[5] = f2b(b.y); r[6] = f2b(b.z); r[7] = f2b(b.w);
  *(u16x8*)(out + i) = r;
}

// W [K][N] f32 -> Wt [N][K] bf16
__global__ __launch_bounds__(256) void transpose_f32_bf16(const float* __restrict__ W,
                                                          unsigned short* __restrict__ Wt,
                                                          int K, int N) {
  __shared__ unsigned short tile[32][33];
  int n0 = blockIdx.x * 32, k0 = blockIdx.y * 32;
  int tx = threadIdx.x, ty = threadIdx.y;  // 32 x 8
  #pragma unroll
  for (int j = 0; j < 32; j += 8)
    tile[ty + j][tx] = f2b(W[(size_t)(k0 + ty + j) * N + n0 + tx]);
  __syncthreads();
  #pragma unroll
  for (int j = 0; j < 32; j += 8)
    Wt[(size_t)(n0 + ty + j) * K + k0 + tx] = tile[tx][ty + j];
}

// ---------------- GEMM: C[M][N] = A[M][K] * Bt[N][K]^T + bias ----------------
// m97 structure: 128x128 tile, BK=64, 4 waves (2x2), 4x4 16x16x32 frags/wave,
// global_load_lds width=16 staging, single-buffered 2-barrier loop.
template <bool OUT_BF16>
__global__ __launch_bounds__(256) void gemm_bt(const unsigned short* __restrict__ A,
                                               const unsigned short* __restrict__ Bt,
                                               const float* __restrict__ bias,
                                               void* __restrict__ Cout,
                                               int M, int N, int K) {
  __shared__ unsigned short As[128 * 64];
  __shared__ unsigned short Bs[128 * 64];
  const int m0 = blockIdx.x * 128, n0 = blockIdx.y * 128;
  const int tid = threadIdx.x;
  const int w = tid >> 6, l = tid & 63;
  const int wm = w >> 1, wn = w & 1;
  const int c = l & 15, g = l >> 4;
  f32x4 acc[4][4] = {};
  for (int k0 = 0; k0 < K; k0 += 64) {
    #pragma unroll
    for (int i = 0; i < 4; ++i) {
      int rb = w * 32 + i * 8;  // wave-uniform LDS base, lane covers (row=rb+l/8, chunk=l%8)
      gload_lds16(A + (size_t)(m0 + rb + (l >> 3)) * K + k0 + (l & 7) * 8, &As[rb * 64]);
      gload_lds16(Bt + (size_t)(n0 + rb + (l >> 3)) * K + k0 + (l & 7) * 8, &Bs[rb * 64]);
    }
    __syncthreads();
    #pragma unroll
    for (int ks = 0; ks < 2; ++ks) {
      bf16x8 af[4], bf[4];
      #pragma unroll
      for (int mi = 0; mi < 4; ++mi)
        af[mi] = *(const bf16x8*)&As[(wm * 64 + mi * 16 + c) * 64 + ks * 32 + g * 8];
      #pragma unroll
      for (int ni = 0; ni < 4; ++ni)
        bf[ni] = *(const bf16x8*)&Bs[(wn * 64 + ni * 16 + c) * 64 + ks * 32 + g * 8];
      #pragma unroll
      for (int mi = 0; mi < 4; ++mi)
        #pragma unroll
        for (int ni = 0; ni < 4; ++ni)
          acc[mi][ni] = __builtin_amdgcn_mfma_f32_16x16x32_bf16(af[mi], bf[ni], acc[mi][ni], 0, 0, 0);
    }
    __syncthreads();
  }
  #pragma unroll
  for (int mi = 0; mi < 4; ++mi) {
    #pragma unroll
    for (int ni = 0; ni < 4; ++ni) {
      int colg = n0 + wn * 64 + ni * 16 + c;
      float bv = bias[colg];
      #pragma unroll
      for (int r = 0; r < 4; ++r) {
        int rowg = m0 + wm * 64 + mi * 16 + 4 * g + r;  // D: row=4*(l>>4)+r, col=l&15
        float v = acc[mi][ni][r] + bv;
        if (OUT_BF16)
          ((unsigned short*)Cout)[(size_t)rowg * N + colg] = f2b(v);
        else
          ((float*)Cout)[(size_t)rowg * N + colg] = v;
      }
    }
  }
}

// ---------------- causal flash attention ----------------
// qkv [4096][3072] bf16 (cols: 0..1023=Q, 1024..2047=K, 2048..3071=V; within: h*64+d)
// out [4096][1024] bf16 (t-major, col=h*64+d)
// 1D grid of 512: heavy q-tiles first (load balance), bid%8 = bh%8 (XCD/L2 locality).
// 4 waves x 32 q-rows, KVBLK=64, K/V double-buffered (T3 minimum 2-phase):
// issue next-tile global loads BEFORE compute, V ds_write after, 1 barrier/tile.
__global__ __launch_bounds__(256) void attn_kernel(const unsigned short* __restrict__ qkv,
                                                   unsigned short* __restrict__ out) {
  __shared__ unsigned short K_lds[2][64 * 64];     // [kv][d], XOR-swizzled rows
  __shared__ unsigned short V_lds[2][64 * 64];     // V^T [d][kv], XOR-swizzled rows
  __shared__ unsigned short P_lds[4 * 32 * 64];    // per-wave [32 q][64 kv], swizzled
  const int bid = blockIdx.x;
  const int qt = 15 - (bid >> 5);                  // heavy-first
  const int bh = bid & 31;
  const int b = bh >> 4, h = bh & 15;
  const int tid = threadIdx.x, w = tid >> 6, l = tid & 63;
  const int c = l & 15, g = l >> 4;
  const int q0 = qt * 128;
  const int q0w = q0 + w * 32;
  const size_t row0 = (size_t)b * 2048;

  // Q fragments in registers: A-frag m=c(+mi*16), k=d=ks*32+8g+e
  bf16x8 qf[2][2];
  #pragma unroll
  for (int mi = 0; mi < 2; ++mi)
    #pragma unroll
    for (int ks = 0; ks < 2; ++ks)
      qf[mi][ks] = *(const bf16x8*)(qkv + (row0 + q0w + mi * 16 + c) * 3072 + h * 64 + ks * 32 + g * 8);

  f32x4 acc[2][4] = {};
  float mstate[2][4], lstate[2][4];
  #pragma unroll
  for (int mi = 0; mi < 2; ++mi)
    #pragma unroll
    for (int r = 0; r < 4; ++r) { mstate[mi][r] = -1e30f; lstate[mi][r] = 0.f; }

  char* Pb = (char*)&P_lds[w * 32 * 64];
  const int vp = tid & 31, vcb = tid >> 5;         // V-stage: kv-pair, d-chunk
  const int nt = 2 * qt + 2;                       // kv tiles (to q0+128)
  const float SCL = 0.18033688f;                   // 0.125 * log2(e): softmax in exp2 domain

  // ---- prologue: stage tile 0 into buffer 0
  {
    #pragma unroll
    for (int i = 0; i < 2; ++i) {
      int rb = w * 16 + i * 8;
      int row = rb + (l >> 3);
      int ch = (l & 7) ^ (row & 7);                // pre-swizzled source (m173)
      gload_lds16(qkv + (row0 + row) * 3072 + 1024 + h * 64 + ch * 8, &K_lds[0][rb * 64]);
    }
    size_t tr = row0 + 2 * vp;
    u16x8 v0 = *(const u16x8*)(qkv + tr * 3072 + 2048 + h * 64 + vcb * 8);
    u16x8 v1 = *(const u16x8*)(qkv + (tr + 1) * 3072 + 2048 + h * 64 + vcb * 8);
    char* Vb = (char*)V_lds[0];
    #pragma unroll
    for (int j = 0; j < 8; ++j) {
      int d = vcb * 8 + j;
      int off = d * 128 + ((4 * vp) ^ ((d & 7) << 4));
      *(unsigned int*)(Vb + off) = (unsigned int)v0[j] | ((unsigned int)v1[j] << 16);
    }
  }
  __syncthreads();

  for (int t = 0; t < nt; ++t) {
    const int cur = t & 1;
    const int kv0 = t * 64;
    const bool pre = (t + 1 < nt);
    u16x8 v0n, v1n;
    if (pre) {
      // issue next-tile loads BEFORE compute: HBM latency hides under MFMA+softmax
      const int kvn = kv0 + 64;
      #pragma unroll
      for (int i = 0; i < 2; ++i) {
        int rb = w * 16 + i * 8;
        int row = rb + (l >> 3);
        int ch = (l & 7) ^ (row & 7);
        gload_lds16(qkv + (row0 + kvn + row) * 3072 + 1024 + h * 64 + ch * 8,
                    &K_lds[cur ^ 1][rb * 64]);
      }
      size_t tr = row0 + kvn + 2 * vp;
      v0n = *(const u16x8*)(qkv + tr * 3072 + 2048 + h * 64 + vcb * 8);
      v1n = *(const u16x8*)(qkv + (tr + 1) * 3072 + 2048 + h * 64 + vcb * 8);
    }
    if (kv0 <= q0w + 31) {  // wave-uniform: skip fully-masked tiles
      const char* Kb = (const char*)K_lds[cur];
      const char* Vb = (const char*)V_lds[cur];
      // ---- S = Q K^T
      f32x4 s[2][4] = {};
      #pragma unroll
      for (int ks = 0; ks < 2; ++ks) {
        bf16x8 kf[4];
        #pragma unroll
        for (int nk = 0; nk < 4; ++nk) {
          int row = nk * 16 + c;
          kf[nk] = *(const bf16x8*)(Kb + row * 128 + ((ks * 64 + g * 16) ^ ((row & 7) << 4)));
        }
        #pragma unroll
        for (int mi = 0; mi < 2; ++mi)
          #pragma unroll
          for (int nk = 0; nk < 4; ++nk)
            s[mi][nk] = __builtin_amdgcn_mfma_f32_16x16x32_bf16(qf[mi][ks], kf[nk], s[mi][nk], 0, 0, 0);
      }
      // ---- scale (exp2 domain) + causal mask (D: row=4g+r(+mi*16), col=c(+nk*16))
      #pragma unroll
      for (int mi = 0; mi < 2; ++mi)
        #pragma unroll
        for (int nk = 0; nk < 4; ++nk)
          #pragma unroll
          for (int r = 0; r < 4; ++r) {
            float v = s[mi][nk][r] * SCL;
            int rowg = q0w + mi * 16 + 4 * g + r;
            int colg = kv0 + nk * 16 + c;
            s[mi][nk][r] = (colg > rowg) ? -1e30f : v;
          }
      // ---- online softmax (rows in 16-lane groups -> 4x shfl_xor per reduce)
      #pragma unroll
      for (int mi = 0; mi < 2; ++mi)
        #pragma unroll
        for (int r = 0; r < 4; ++r) {
          float mx = fmaxf(fmaxf(s[mi][0][r], s[mi][1][r]), fmaxf(s[mi][2][r], s[mi][3][r]));
          mx = fmaxf(mx, __shfl_xor(mx, 1));
          mx = fmaxf(mx, __shfl_xor(mx, 2));
          mx = fmaxf(mx, __shfl_xor(mx, 4));
          mx = fmaxf(mx, __shfl_xor(mx, 8));
          float mold = mstate[mi][r];
          float mnew = fmaxf(mold, mx);
          float alpha = exp2f(mold - mnew);
          mstate[mi][r] = mnew;
          float rs = 0.f;
          #pragma unroll
          for (int nk = 0; nk < 4; ++nk) {
            float p = exp2f(s[mi][nk][r] - mnew);
            s[mi][nk][r] = p;
            rs += p;
          }
          rs += __shfl_xor(rs, 1);
          rs += __shfl_xor(rs, 2);
          rs += __shfl_xor(rs, 4);
          rs += __shfl_xor(rs, 8);
          lstate[mi][r] = lstate[mi][r] * alpha + rs;
          #pragma unroll
          for (int nd = 0; nd < 4; ++nd) acc[mi][nd][r] *= alpha;
        }
      // ---- P -> LDS (bf16, swizzled; per-wave buffer, in-wave lgkm sync only)
      #pragma unroll
      for (int mi = 0; mi < 2; ++mi)
        #pragma unroll
        for (int nk = 0; nk < 4; ++nk)
          #pragma unroll
          for (int r = 0; r < 4; ++r) {
            int row = mi * 16 + 4 * g + r;
            int off = row * 128 + (((nk * 16 + c) * 2) ^ ((row & 7) << 4));
            *(unsigned short*)(Pb + off) = f2b(s[mi][nk][r]);
          }
      // ---- O += P V
      #pragma unroll
      for (int ks = 0; ks < 2; ++ks) {
        bf16x8 pf[2], vf[4];
        #pragma unroll
        for (int mi = 0; mi < 2; ++mi) {
          int row = mi * 16 + c;
          pf[mi] = *(const bf16x8*)(Pb + row * 128 + ((ks * 64 + g * 16) ^ ((row & 7) << 4)));
        }
        #pragma unroll
        for (int nd = 0; nd < 4; ++nd) {
          int row = nd * 16 + c;
          vf[nd] = *(const bf16x8*)(Vb + row * 128 + ((ks * 64 + g * 16) ^ ((row & 7) << 4)));
        }
        #pragma unroll
        for (int mi = 0; mi < 2; ++mi)
          #pragma unroll
          for (int nd = 0; nd < 4; ++nd)
            acc[mi][nd] = __builtin_amdgcn_mfma_f32_16x16x32_bf16(pf[mi], vf[nd], acc[mi][nd], 0, 0, 0);
      }
    }
    if (pre) {
      // write prefetched V into the next buffer (compiler inserts vmcnt wait here)
      char* Vb = (char*)V_lds[cur ^ 1];
      #pragma unroll
      for (int j = 0; j < 8; ++j) {
        int d = vcb * 8 + j;
        int off = d * 128 + ((4 * vp) ^ ((d & 7) << 4));
        *(unsigned int*)(Vb + off) = (unsigned int)v0n[j] | ((unsigned int)v1n[j] << 16);
      }
    }
    __syncthreads();  // one barrier per tile: drains gload_lds + V ds_writes
  }
  // ---- epilogue: O /= l, write bf16 [t][h*64+d]
  #pragma unroll
  for (int mi = 0; mi < 2; ++mi)
    #pragma unroll
    for (int r = 0; r < 4; ++r) {
      float rinv = 1.0f / lstate[mi][r];
      size_t t = row0 + q0w + mi * 16 + 4 * g + r;
      #pragma unroll
      for (int nd = 0; nd < 4; ++nd)
        out[t * 1024 + h * 64 + nd * 16 + c] = f2b(acc[mi][nd][r] * rinv);
    }
}

// ---------------- launch ----------------
extern "C" void kernel_launch(void* const* d_in, const int* in_sizes, int n_in,
                              void* d_out, int out_size, void* d_ws, size_t ws_size,
                              hipStream_t stream) {
  const float* x      = (const float*)d_in[0];
  const float* W_attn = (const float*)d_in[1];
  const float* b_attn = (const float*)d_in[2];
  const float* W_proj = (const float*)d_in[3];
  const float* b_proj = (const float*)d_in[4];
  float* out = (float*)d_out;

  char* ws = (char*)d_ws;
  unsigned short* x_bf     = (unsigned short*)(ws + 0);           //  8 MB [4096][1024]
  unsigned short* Wattn_t  = (unsigned short*)(ws + 8388608);     //  6 MB [3072][1024]
  unsigned short* Wproj_t  = (unsigned short*)(ws + 14680064);    //  2 MB [1024][1024]
  unsigned short* qkv      = (unsigned short*)(ws + 16777216);    // 24 MB [4096][3072]
  unsigned short* attn_out = (unsigned short*)(ws + 41943040);    //  8 MB [4096][1024]
  // total ws use: 48 MB

  convert_f32_bf16<<<2048, 256, 0, stream>>>(x, x_bf, 4194304);
  transpose_f32_bf16<<<dim3(96, 32), dim3(32, 8), 0, stream>>>(W_attn, Wattn_t, 1024, 3072);
  transpose_f32_bf16<<<dim3(32, 32), dim3(32, 8), 0, stream>>>(W_proj, Wproj_t, 1024, 1024);

  gemm_bt<true><<<dim3(32, 24), 256, 0, stream>>>(x_bf, Wattn_t, b_attn, qkv, 4096, 3072, 1024);
  attn_kernel<<<512, 256, 0, stream>>>(qkv, attn_out);
  gemm_bt<false><<<dim3(32, 8), 256, 0, stream>>>(attn_out, Wproj_t, b_proj, out, 4096, 1024, 1024);
}

// Round 3
// 167.138 us; speedup vs baseline: 1.2705x; 1.2324x over previous
//
#include <hip/hip_runtime.h>
#include <stdint.h>

typedef __attribute__((ext_vector_type(4))) float f32x4;
typedef __attribute__((ext_vector_type(8))) __bf16 bf16x8;
typedef __attribute__((ext_vector_type(8))) unsigned short u16x8;

__device__ __forceinline__ unsigned short f2b(float f) {
  unsigned u = __float_as_uint(f);
  u += 0x7FFFu + ((u >> 16) & 1u);   // RNE
  return (unsigned short)(u >> 16);
}

__device__ __forceinline__ void gload_lds16(const void* g, void* l) {
  typedef __attribute__((address_space(1))) void GV1;
  typedef __attribute__((address_space(3))) void LV3;
  __builtin_amdgcn_global_load_lds((GV1*)(void*)g, (LV3*)l, 16, 0, 0);
}

// ---------------- conversion kernels ----------------
__global__ __launch_bounds__(256) void convert_f32_bf16(const float* __restrict__ in,
                                                        unsigned short* __restrict__ out, int n) {
  int i = (blockIdx.x * 256 + threadIdx.x) * 8;
  if (i >= n) return;
  float4 a = *(const float4*)(in + i);
  float4 b = *(const float4*)(in + i + 4);
  u16x8 r;
  r[0] = f2b(a.x); r[1] = f2b(a.y); r[2] = f2b(a.z); r[3] = f2b(a.w);
  r[4] = f2b(b.x); r[5] = f2b(b.y); r[6] = f2b(b.z); r[7] = f2b(b.w);
  *(u16x8*)(out + i) = r;
}

// W [K][N] f32 -> Wt [N][K] bf16
__global__ __launch_bounds__(256) void transpose_f32_bf16(const float* __restrict__ W,
                                                          unsigned short* __restrict__ Wt,
                                                          int K, int N) {
  __shared__ unsigned short tile[32][33];
  int n0 = blockIdx.x * 32, k0 = blockIdx.y * 32;
  int tx = threadIdx.x, ty = threadIdx.y;  // 32 x 8
  #pragma unroll
  for (int j = 0; j < 32; j += 8)
    tile[ty + j][tx] = f2b(W[(size_t)(k0 + ty + j) * N + n0 + tx]);
  __syncthreads();
  #pragma unroll
  for (int j = 0; j < 32; j += 8)
    Wt[(size_t)(n0 + ty + j) * K + k0 + tx] = tile[tx][ty + j];
}

// ---------------- GEMM: C[M][N] = A[M][K] * Bt[N][K]^T + bias ----------------
template <bool OUT_BF16>
__global__ __launch_bounds__(256) void gemm_bt(const unsigned short* __restrict__ A,
                                               const unsigned short* __restrict__ Bt,
                                               const float* __restrict__ bias,
                                               void* __restrict__ Cout,
                                               int M, int N, int K) {
  __shared__ unsigned short As[128 * 64];
  __shared__ unsigned short Bs[128 * 64];
  const int m0 = blockIdx.x * 128, n0 = blockIdx.y * 128;
  const int tid = threadIdx.x;
  const int w = tid >> 6, l = tid & 63;
  const int wm = w >> 1, wn = w & 1;
  const int c = l & 15, g = l >> 4;
  f32x4 acc[4][4] = {};
  for (int k0 = 0; k0 < K; k0 += 64) {
    #pragma unroll
    for (int i = 0; i < 4; ++i) {
      int rb = w * 32 + i * 8;
      gload_lds16(A + (size_t)(m0 + rb + (l >> 3)) * K + k0 + (l & 7) * 8, &As[rb * 64]);
      gload_lds16(Bt + (size_t)(n0 + rb + (l >> 3)) * K + k0 + (l & 7) * 8, &Bs[rb * 64]);
    }
    __syncthreads();
    #pragma unroll
    for (int ks = 0; ks < 2; ++ks) {
      bf16x8 af[4], bf[4];
      #pragma unroll
      for (int mi = 0; mi < 4; ++mi)
        af[mi] = *(const bf16x8*)&As[(wm * 64 + mi * 16 + c) * 64 + ks * 32 + g * 8];
      #pragma unroll
      for (int ni = 0; ni < 4; ++ni)
        bf[ni] = *(const bf16x8*)&Bs[(wn * 64 + ni * 16 + c) * 64 + ks * 32 + g * 8];
      #pragma unroll
      for (int mi = 0; mi < 4; ++mi)
        #pragma unroll
        for (int ni = 0; ni < 4; ++ni)
          acc[mi][ni] = __builtin_amdgcn_mfma_f32_16x16x32_bf16(af[mi], bf[ni], acc[mi][ni], 0, 0, 0);
    }
    __syncthreads();
  }
  #pragma unroll
  for (int mi = 0; mi < 4; ++mi) {
    #pragma unroll
    for (int ni = 0; ni < 4; ++ni) {
      int colg = n0 + wn * 64 + ni * 16 + c;
      float bv = bias[colg];
      #pragma unroll
      for (int r = 0; r < 4; ++r) {
        int rowg = m0 + wm * 64 + mi * 16 + 4 * g + r;
        float v = acc[mi][ni][r] + bv;
        if (OUT_BF16)
          ((unsigned short*)Cout)[(size_t)rowg * N + colg] = f2b(v);
        else
          ((float*)Cout)[(size_t)rowg * N + colg] = v;
      }
    }
  }
}

// ---------------- causal flash attention ----------------
// qkv [4096][3072] bf16; out [4096][1024] bf16.
// UNIFORM-WORK blocks: 64-row q-tiles (32 per bh); block handles pair (pj, 31-pj)
// -> (pj+1) + (32-pj) = 33 kv-tiles per block, exactly uniform across 512 blocks.
// 4 waves x 16 q-rows. K/V double-buffered 2-phase (prefetch before compute).
// bid&31 = bh -> all blocks of one (b,h) share an XCD's L2 (R1: FETCH 55->12MB).
__global__ __launch_bounds__(256) void attn_kernel(const unsigned short* __restrict__ qkv,
                                                   unsigned short* __restrict__ out) {
  __shared__ unsigned short K_lds[2][64 * 64];     // [kv][d], XOR-swizzled rows
  __shared__ unsigned short V_lds[2][64 * 64];     // V^T [d][kv], XOR-swizzled rows
  __shared__ unsigned short P_lds[4 * 16 * 64];    // per-wave [16 q][64 kv], swizzled
  const int bid = blockIdx.x;
  const int pj = bid >> 5;                         // 0..15
  const int bh = bid & 31;
  const int b = bh >> 4, h = bh & 15;
  const int tid = threadIdx.x, w = tid >> 6, l = tid & 63;
  const int c = l & 15, g = l >> 4;
  const size_t row0 = (size_t)b * 2048;
  const int vp = tid & 31, vcb = tid >> 5;         // V-stage: kv-pair, d-chunk
  const float SCL = 0.18033688f;                   // 0.125 * log2(e): exp2 domain
  char* Pb = (char*)&P_lds[w * 16 * 64];

  for (int seg = 0; seg < 2; ++seg) {
    const int qt = seg ? (31 - pj) : pj;
    const int q0 = qt * 64;
    const int q0w = q0 + w * 16;
    const int nt = qt + 1;

    // Q fragments: A-frag m=c, k=d=ks*32+8g+e
    bf16x8 qf[2];
    #pragma unroll
    for (int ks = 0; ks < 2; ++ks)
      qf[ks] = *(const bf16x8*)(qkv + (row0 + q0w + c) * 3072 + h * 64 + ks * 32 + g * 8);

    f32x4 acc[4] = {};
    float mstate[4], lstate[4];
    #pragma unroll
    for (int r = 0; r < 4; ++r) { mstate[r] = -1e30f; lstate[r] = 0.f; }

    // ---- prologue: stage kv-tile 0 into buffer 0
    {
      #pragma unroll
      for (int i = 0; i < 2; ++i) {
        int rb = w * 16 + i * 8;
        int row = rb + (l >> 3);
        int ch = (l & 7) ^ (row & 7);              // pre-swizzled source (m173)
        gload_lds16(qkv + (row0 + row) * 3072 + 1024 + h * 64 + ch * 8, &K_lds[0][rb * 64]);
      }
      size_t tr = row0 + 2 * vp;
      u16x8 v0 = *(const u16x8*)(qkv + tr * 3072 + 2048 + h * 64 + vcb * 8);
      u16x8 v1 = *(const u16x8*)(qkv + (tr + 1) * 3072 + 2048 + h * 64 + vcb * 8);
      char* Vb = (char*)V_lds[0];
      #pragma unroll
      for (int j = 0; j < 8; ++j) {
        int d = vcb * 8 + j;
        int off = d * 128 + ((4 * vp) ^ ((d & 7) << 4));
        *(unsigned int*)(Vb + off) = (unsigned int)v0[j] | ((unsigned int)v1[j] << 16);
      }
    }
    __syncthreads();

    for (int t = 0; t < nt; ++t) {
      const int cur = t & 1;
      const int kv0 = t * 64;
      const bool pre = (t + 1 < nt);
      u16x8 v0n, v1n;
      if (pre) {  // issue next-tile loads BEFORE compute (2-phase pipeline)
        const int kvn = kv0 + 64;
        #pragma unroll
        for (int i = 0; i < 2; ++i) {
          int rb = w * 16 + i * 8;
          int row = rb + (l >> 3);
          int ch = (l & 7) ^ (row & 7);
          gload_lds16(qkv + (row0 + kvn + row) * 3072 + 1024 + h * 64 + ch * 8,
                      &K_lds[cur ^ 1][rb * 64]);
        }
        size_t tr = row0 + kvn + 2 * vp;
        v0n = *(const u16x8*)(qkv + tr * 3072 + 2048 + h * 64 + vcb * 8);
        v1n = *(const u16x8*)(qkv + (tr + 1) * 3072 + 2048 + h * 64 + vcb * 8);
      }
      const char* Kb = (const char*)K_lds[cur];
      const char* Vb = (const char*)V_lds[cur];
      // ---- S = Q K^T
      f32x4 s[4] = {};
      #pragma unroll
      for (int ks = 0; ks < 2; ++ks) {
        bf16x8 kf[4];
        #pragma unroll
        for (int nk = 0; nk < 4; ++nk) {
          int row = nk * 16 + c;
          kf[nk] = *(const bf16x8*)(Kb + row * 128 + ((ks * 64 + g * 16) ^ ((row & 7) << 4)));
        }
        __builtin_amdgcn_s_setprio(1);
        #pragma unroll
        for (int nk = 0; nk < 4; ++nk)
          s[nk] = __builtin_amdgcn_mfma_f32_16x16x32_bf16(qf[ks], kf[nk], s[nk], 0, 0, 0);
        __builtin_amdgcn_s_setprio(0);
      }
      // ---- scale (+ mask only on the diagonal tile; wave-uniform branch)
      if (t == nt - 1) {
        #pragma unroll
        for (int nk = 0; nk < 4; ++nk)
          #pragma unroll
          for (int r = 0; r < 4; ++r) {
            float v = s[nk][r] * SCL;
            int rowg = q0w + 4 * g + r;
            int colg = kv0 + nk * 16 + c;
            s[nk][r] = (colg > rowg) ? -1e30f : v;
          }
      } else {
        #pragma unroll
        for (int nk = 0; nk < 4; ++nk)
          #pragma unroll
          for (int r = 0; r < 4; ++r) s[nk][r] *= SCL;
      }
      // ---- online softmax (row = 4g+r, cols across c-lanes -> 4x shfl_xor)
      #pragma unroll
      for (int r = 0; r < 4; ++r) {
        float mx = fmaxf(fmaxf(s[0][r], s[1][r]), fmaxf(s[2][r], s[3][r]));
        mx = fmaxf(mx, __shfl_xor(mx, 1));
        mx = fmaxf(mx, __shfl_xor(mx, 2));
        mx = fmaxf(mx, __shfl_xor(mx, 4));
        mx = fmaxf(mx, __shfl_xor(mx, 8));
        float mold = mstate[r];
        float mnew = fmaxf(mold, mx);
        float alpha = exp2f(mold - mnew);
        mstate[r] = mnew;
        float rs = 0.f;
        #pragma unroll
        for (int nk = 0; nk < 4; ++nk) {
          float p = exp2f(s[nk][r] - mnew);
          s[nk][r] = p;
          rs += p;
        }
        rs += __shfl_xor(rs, 1);
        rs += __shfl_xor(rs, 2);
        rs += __shfl_xor(rs, 4);
        rs += __shfl_xor(rs, 8);
        lstate[r] = lstate[r] * alpha + rs;
        #pragma unroll
        for (int nd = 0; nd < 4; ++nd) acc[nd][r] *= alpha;
      }
      // ---- P -> LDS (bf16, swizzled; per-wave buffer, in-wave lgkm sync only)
      #pragma unroll
      for (int nk = 0; nk < 4; ++nk)
        #pragma unroll
        for (int r = 0; r < 4; ++r) {
          int row = 4 * g + r;
          int off = row * 128 + (((nk * 16 + c) * 2) ^ ((row & 7) << 4));
          *(unsigned short*)(Pb + off) = f2b(s[nk][r]);
        }
      // ---- O += P V
      #pragma unroll
      for (int ks = 0; ks < 2; ++ks) {
        bf16x8 pf, vf[4];
        pf = *(const bf16x8*)(Pb + c * 128 + ((ks * 64 + g * 16) ^ ((c & 7) << 4)));
        #pragma unroll
        for (int nd = 0; nd < 4; ++nd) {
          int row = nd * 16 + c;
          vf[nd] = *(const bf16x8*)(Vb + row * 128 + ((ks * 64 + g * 16) ^ ((row & 7) << 4)));
        }
        __builtin_amdgcn_s_setprio(1);
        #pragma unroll
        for (int nd = 0; nd < 4; ++nd)
          acc[nd] = __builtin_amdgcn_mfma_f32_16x16x32_bf16(pf, vf[nd], acc[nd], 0, 0, 0);
        __builtin_amdgcn_s_setprio(0);
      }
      if (pre) {  // write prefetched V into next buffer (vmcnt wait lands here)
        char* Vbn = (char*)V_lds[cur ^ 1];
        #pragma unroll
        for (int j = 0; j < 8; ++j) {
          int d = vcb * 8 + j;
          int off = d * 128 + ((4 * vp) ^ ((d & 7) << 4));
          *(unsigned int*)(Vbn + off) = (unsigned int)v0n[j] | ((unsigned int)v1n[j] << 16);
        }
      }
      __syncthreads();  // one barrier per tile
    }
    // ---- epilogue: O /= l, write bf16 [t][h*64+d]
    #pragma unroll
    for (int r = 0; r < 4; ++r) {
      float rinv = 1.0f / lstate[r];
      size_t t = row0 + q0w + 4 * g + r;
      #pragma unroll
      for (int nd = 0; nd < 4; ++nd)
        out[t * 1024 + h * 64 + nd * 16 + c] = f2b(acc[nd][r] * rinv);
    }
  }
}

// ---------------- launch ----------------
extern "C" void kernel_launch(void* const* d_in, const int* in_sizes, int n_in,
                              void* d_out, int out_size, void* d_ws, size_t ws_size,
                              hipStream_t stream) {
  const float* x      = (const float*)d_in[0];
  const float* W_attn = (const float*)d_in[1];
  const float* b_attn = (const float*)d_in[2];
  const float* W_proj = (const float*)d_in[3];
  const float* b_proj = (const float*)d_in[4];
  float* out = (float*)d_out;

  char* ws = (char*)d_ws;
  unsigned short* x_bf     = (unsigned short*)(ws + 0);           //  8 MB [4096][1024]
  unsigned short* Wattn_t  = (unsigned short*)(ws + 8388608);     //  6 MB [3072][1024]
  unsigned short* Wproj_t  = (unsigned short*)(ws + 14680064);    //  2 MB [1024][1024]
  unsigned short* qkv      = (unsigned short*)(ws + 16777216);    // 24 MB [4096][3072]
  unsigned short* attn_out = (unsigned short*)(ws + 41943040);    //  8 MB [4096][1024]

  convert_f32_bf16<<<2048, 256, 0, stream>>>(x, x_bf, 4194304);
  transpose_f32_bf16<<<dim3(96, 32), dim3(32, 8), 0, stream>>>(W_attn, Wattn_t, 1024, 3072);
  transpose_f32_bf16<<<dim3(32, 32), dim3(32, 8), 0, stream>>>(W_proj, Wproj_t, 1024, 1024);

  gemm_bt<true><<<dim3(32, 24), 256, 0, stream>>>(x_bf, Wattn_t, b_attn, qkv, 4096, 3072, 1024);
  attn_kernel<<<512, 256, 0, stream>>>(qkv, attn_out);
  gemm_bt<false><<<dim3(32, 8), 256, 0, stream>>>(attn_out, Wproj_t, b_proj, out, 4096, 1024, 1024);
}

// Round 4
// 163.554 us; speedup vs baseline: 1.2984x; 1.0219x over previous
//
#include <hip/hip_runtime.h>
#include <stdint.h>

typedef __attribute__((ext_vector_type(4))) float f32x4;
typedef __attribute__((ext_vector_type(8))) __bf16 bf16x8;
typedef __attribute__((ext_vector_type(8))) unsigned short u16x8;

__device__ __forceinline__ unsigned short f2b(float f) {
  unsigned u = __float_as_uint(f);
  u += 0x7FFFu + ((u >> 16) & 1u);   // RNE
  return (unsigned short)(u >> 16);
}

__device__ __forceinline__ void gload_lds16(const void* g, void* l) {
  typedef __attribute__((address_space(1))) void GV1;
  typedef __attribute__((address_space(3))) void LV3;
  __builtin_amdgcn_global_load_lds((GV1*)(void*)g, (LV3*)l, 16, 0, 0);
}

// ---------------- conversion kernels ----------------
__global__ __launch_bounds__(256) void convert_f32_bf16(const float* __restrict__ in,
                                                        unsigned short* __restrict__ out, int n) {
  int i = (blockIdx.x * 256 + threadIdx.x) * 8;
  if (i >= n) return;
  float4 a = *(const float4*)(in + i);
  float4 b = *(const float4*)(in + i + 4);
  u16x8 r;
  r[0] = f2b(a.x); r[1] = f2b(a.y); r[2] = f2b(a.z); r[3] = f2b(a.w);
  r[4] = f2b(b.x); r[5] = f2b(b.y); r[6] = f2b(b.z); r[7] = f2b(b.w);
  *(u16x8*)(out + i) = r;
}

// W [K][N] f32 -> Wt [N][K] bf16
__global__ __launch_bounds__(256) void transpose_f32_bf16(const float* __restrict__ W,
                                                          unsigned short* __restrict__ Wt,
                                                          int K, int N) {
  __shared__ unsigned short tile[32][33];
  int n0 = blockIdx.x * 32, k0 = blockIdx.y * 32;
  int tx = threadIdx.x, ty = threadIdx.y;  // 32 x 8
  #pragma unroll
  for (int j = 0; j < 32; j += 8)
    tile[ty + j][tx] = f2b(W[(size_t)(k0 + ty + j) * N + n0 + tx]);
  __syncthreads();
  #pragma unroll
  for (int j = 0; j < 32; j += 8)
    Wt[(size_t)(n0 + ty + j) * K + k0 + tx] = tile[tx][ty + j];
}

// ---------------- GEMM: C[M][N] = A[M][K] * Bt[N][K]^T + bias ----------------
template <bool OUT_BF16>
__global__ __launch_bounds__(256) void gemm_bt(const unsigned short* __restrict__ A,
                                               const unsigned short* __restrict__ Bt,
                                               const float* __restrict__ bias,
                                               void* __restrict__ Cout,
                                               int M, int N, int K) {
  __shared__ unsigned short As[128 * 64];
  __shared__ unsigned short Bs[128 * 64];
  const int m0 = blockIdx.x * 128, n0 = blockIdx.y * 128;
  const int tid = threadIdx.x;
  const int w = tid >> 6, l = tid & 63;
  const int wm = w >> 1, wn = w & 1;
  const int c = l & 15, g = l >> 4;
  f32x4 acc[4][4] = {};
  for (int k0 = 0; k0 < K; k0 += 64) {
    #pragma unroll
    for (int i = 0; i < 4; ++i) {
      int rb = w * 32 + i * 8;
      gload_lds16(A + (size_t)(m0 + rb + (l >> 3)) * K + k0 + (l & 7) * 8, &As[rb * 64]);
      gload_lds16(Bt + (size_t)(n0 + rb + (l >> 3)) * K + k0 + (l & 7) * 8, &Bs[rb * 64]);
    }
    __syncthreads();
    #pragma unroll
    for (int ks = 0; ks < 2; ++ks) {
      bf16x8 af[4], bf[4];
      #pragma unroll
      for (int mi = 0; mi < 4; ++mi)
        af[mi] = *(const bf16x8*)&As[(wm * 64 + mi * 16 + c) * 64 + ks * 32 + g * 8];
      #pragma unroll
      for (int ni = 0; ni < 4; ++ni)
        bf[ni] = *(const bf16x8*)&Bs[(wn * 64 + ni * 16 + c) * 64 + ks * 32 + g * 8];
      #pragma unroll
      for (int mi = 0; mi < 4; ++mi)
        #pragma unroll
        for (int ni = 0; ni < 4; ++ni)
          acc[mi][ni] = __builtin_amdgcn_mfma_f32_16x16x32_bf16(af[mi], bf[ni], acc[mi][ni], 0, 0, 0);
    }
    __syncthreads();
  }
  #pragma unroll
  for (int mi = 0; mi < 4; ++mi) {
    #pragma unroll
    for (int ni = 0; ni < 4; ++ni) {
      int colg = n0 + wn * 64 + ni * 16 + c;
      float bv = bias[colg];
      #pragma unroll
      for (int r = 0; r < 4; ++r) {
        int rowg = m0 + wm * 64 + mi * 16 + 4 * g + r;
        float v = acc[mi][ni][r] + bv;
        if (OUT_BF16)
          ((unsigned short*)Cout)[(size_t)rowg * N + colg] = f2b(v);
        else
          ((float*)Cout)[(size_t)rowg * N + colg] = v;
      }
    }
  }
}

// ---------------- causal flash attention ----------------
// qkv [4096][3072] bf16; out [4096][1024] bf16.
// 1024 blocks: each block ONE 64-row q-tile. qt = 31-bid/32 (heavy-first ->
// per-CU qt-band mix balances statistically at 4 blocks/CU), bh = bid&31
// (XCD/L2 locality, R1: FETCH 55->12MB). 4 waves x 16 q-rows. K/V double-
// buffered 2-phase. LDS 40KB -> exactly 4 blocks/CU (occupancy cap 50%).
__global__ __launch_bounds__(256) void attn_kernel(const unsigned short* __restrict__ qkv,
                                                   unsigned short* __restrict__ out) {
  __shared__ unsigned short K_lds[2][64 * 64];     // [kv][d], XOR-swizzled rows
  __shared__ unsigned short V_lds[2][64 * 64];     // V^T [d][kv], XOR-swizzled rows
  __shared__ unsigned short P_lds[4 * 16 * 64];    // per-wave [16 q][64 kv], swizzled
  const int bid = blockIdx.x;
  const int qt = 31 - (bid >> 5);                  // heavy-first
  const int bh = bid & 31;
  const int b = bh >> 4, h = bh & 15;
  const int tid = threadIdx.x, w = tid >> 6, l = tid & 63;
  const int c = l & 15, g = l >> 4;
  const size_t row0 = (size_t)b * 2048;
  const int vp = tid & 31, vcb = tid >> 5;         // V-stage: kv-pair, d-chunk
  const float SCL = 0.18033688f;                   // 0.125 * log2(e): exp2 domain
  char* Pb = (char*)&P_lds[w * 16 * 64];

  const int q0 = qt * 64;
  const int q0w = q0 + w * 16;
  const int nt = qt + 1;

  // Q fragments: A-frag m=c, k=d=ks*32+8g+e
  bf16x8 qf[2];
  #pragma unroll
  for (int ks = 0; ks < 2; ++ks)
    qf[ks] = *(const bf16x8*)(qkv + (row0 + q0w + c) * 3072 + h * 64 + ks * 32 + g * 8);

  f32x4 acc[4] = {};
  float mstate[4], lstate[4];                      // mstate in RAW score domain
  #pragma unroll
  for (int r = 0; r < 4; ++r) { mstate[r] = -1e30f; lstate[r] = 0.f; }

  // ---- prologue: stage kv-tile 0 into buffer 0
  {
    #pragma unroll
    for (int i = 0; i < 2; ++i) {
      int rb = w * 16 + i * 8;
      int row = rb + (l >> 3);
      int ch = (l & 7) ^ (row & 7);                // pre-swizzled source (m173)
      gload_lds16(qkv + (row0 + row) * 3072 + 1024 + h * 64 + ch * 8, &K_lds[0][rb * 64]);
    }
    size_t tr = row0 + 2 * vp;
    u16x8 v0 = *(const u16x8*)(qkv + tr * 3072 + 2048 + h * 64 + vcb * 8);
    u16x8 v1 = *(const u16x8*)(qkv + (tr + 1) * 3072 + 2048 + h * 64 + vcb * 8);
    char* Vb = (char*)V_lds[0];
    #pragma unroll
    for (int j = 0; j < 8; ++j) {
      int d = vcb * 8 + j;
      int off = d * 128 + ((4 * vp) ^ ((d & 7) << 4));
      *(unsigned int*)(Vb + off) = (unsigned int)v0[j] | ((unsigned int)v1[j] << 16);
    }
  }
  __syncthreads();

  for (int t = 0; t < nt; ++t) {
    const int cur = t & 1;
    const int kv0 = t * 64;
    const bool pre = (t + 1 < nt);
    u16x8 v0n, v1n;
    if (pre) {  // issue next-tile loads BEFORE compute (2-phase pipeline)
      const int kvn = kv0 + 64;
      #pragma unroll
      for (int i = 0; i < 2; ++i) {
        int rb = w * 16 + i * 8;
        int row = rb + (l >> 3);
        int ch = (l & 7) ^ (row & 7);
        gload_lds16(qkv + (row0 + kvn + row) * 3072 + 1024 + h * 64 + ch * 8,
                    &K_lds[cur ^ 1][rb * 64]);
      }
      size_t tr = row0 + kvn + 2 * vp;
      v0n = *(const u16x8*)(qkv + tr * 3072 + 2048 + h * 64 + vcb * 8);
      v1n = *(const u16x8*)(qkv + (tr + 1) * 3072 + 2048 + h * 64 + vcb * 8);
    }
    const char* Kb = (const char*)K_lds[cur];
    const char* Vb = (const char*)V_lds[cur];
    // ---- S = Q K^T (raw scores; scale folded into exp2 FMA below)
    f32x4 s[4] = {};
    #pragma unroll
    for (int ks = 0; ks < 2; ++ks) {
      bf16x8 kf[4];
      #pragma unroll
      for (int nk = 0; nk < 4; ++nk) {
        int row = nk * 16 + c;
        kf[nk] = *(const bf16x8*)(Kb + row * 128 + ((ks * 64 + g * 16) ^ ((row & 7) << 4)));
      }
      __builtin_amdgcn_s_setprio(1);
      #pragma unroll
      for (int nk = 0; nk < 4; ++nk)
        s[nk] = __builtin_amdgcn_mfma_f32_16x16x32_bf16(qf[ks], kf[nk], s[nk], 0, 0, 0);
      __builtin_amdgcn_s_setprio(0);
    }
    // ---- causal mask only on the diagonal tile (wave-uniform branch), raw domain
    if (t == nt - 1) {
      #pragma unroll
      for (int nk = 0; nk < 4; ++nk)
        #pragma unroll
        for (int r = 0; r < 4; ++r) {
          int rowg = q0w + 4 * g + r;
          int colg = kv0 + nk * 16 + c;
          if (colg > rowg) s[nk][r] = -1e30f;
        }
    }
    // ---- online softmax (raw-domain max; exp2(s*SCL - m*SCL) via FMA)
    #pragma unroll
    for (int r = 0; r < 4; ++r) {
      float mx = fmaxf(fmaxf(s[0][r], s[1][r]), fmaxf(s[2][r], s[3][r]));
      mx = fmaxf(mx, __shfl_xor(mx, 1));
      mx = fmaxf(mx, __shfl_xor(mx, 2));
      mx = fmaxf(mx, __shfl_xor(mx, 4));
      mx = fmaxf(mx, __shfl_xor(mx, 8));
      float mold = mstate[r];
      float mnew = fmaxf(mold, mx);
      float alpha = exp2f((mold - mnew) * SCL);
      mstate[r] = mnew;
      float ms = mnew * SCL;
      float rs = 0.f;
      #pragma unroll
      for (int nk = 0; nk < 4; ++nk) {
        float p = exp2f(fmaf(s[nk][r], SCL, -ms));
        s[nk][r] = p;
        rs += p;
      }
      rs += __shfl_xor(rs, 1);
      rs += __shfl_xor(rs, 2);
      rs += __shfl_xor(rs, 4);
      rs += __shfl_xor(rs, 8);
      lstate[r] = lstate[r] * alpha + rs;
      #pragma unroll
      for (int nd = 0; nd < 4; ++nd) acc[nd][r] *= alpha;
    }
    // ---- P -> LDS (bf16, swizzled; per-wave buffer, in-wave lgkm sync only)
    #pragma unroll
    for (int nk = 0; nk < 4; ++nk)
      #pragma unroll
      for (int r = 0; r < 4; ++r) {
        int row = 4 * g + r;
        int off = row * 128 + (((nk * 16 + c) * 2) ^ ((row & 7) << 4));
        *(unsigned short*)(Pb + off) = f2b(s[nk][r]);
      }
    // ---- O += P V
    #pragma unroll
    for (int ks = 0; ks < 2; ++ks) {
      bf16x8 pf, vf[4];
      pf = *(const bf16x8*)(Pb + c * 128 + ((ks * 64 + g * 16) ^ ((c & 7) << 4)));
      #pragma unroll
      for (int nd = 0; nd < 4; ++nd) {
        int row = nd * 16 + c;
        vf[nd] = *(const bf16x8*)(Vb + row * 128 + ((ks * 64 + g * 16) ^ ((row & 7) << 4)));
      }
      __builtin_amdgcn_s_setprio(1);
      #pragma unroll
      for (int nd = 0; nd < 4; ++nd)
        acc[nd] = __builtin_amdgcn_mfma_f32_16x16x32_bf16(pf, vf[nd], acc[nd], 0, 0, 0);
      __builtin_amdgcn_s_setprio(0);
    }
    if (pre) {  // write prefetched V into next buffer (vmcnt wait lands here)
      char* Vbn = (char*)V_lds[cur ^ 1];
      #pragma unroll
      for (int j = 0; j < 8; ++j) {
        int d = vcb * 8 + j;
        int off = d * 128 + ((4 * vp) ^ ((d & 7) << 4));
        *(unsigned int*)(Vbn + off) = (unsigned int)v0n[j] | ((unsigned int)v1n[j] << 16);
      }
    }
    __syncthreads();  // one barrier per tile
  }
  // ---- epilogue: O /= l, write bf16 [t][h*64+d]
  #pragma unroll
  for (int r = 0; r < 4; ++r) {
    float rinv = 1.0f / lstate[r];
    size_t t = row0 + q0w + 4 * g + r;
    #pragma unroll
    for (int nd = 0; nd < 4; ++nd)
      out[t * 1024 + h * 64 + nd * 16 + c] = f2b(acc[nd][r] * rinv);
  }
}

// ---------------- launch ----------------
extern "C" void kernel_launch(void* const* d_in, const int* in_sizes, int n_in,
                              void* d_out, int out_size, void* d_ws, size_t ws_size,
                              hipStream_t stream) {
  const float* x      = (const float*)d_in[0];
  const float* W_attn = (const float*)d_in[1];
  const float* b_attn = (const float*)d_in[2];
  const float* W_proj = (const float*)d_in[3];
  const float* b_proj = (const float*)d_in[4];
  float* out = (float*)d_out;

  char* ws = (char*)d_ws;
  unsigned short* x_bf     = (unsigned short*)(ws + 0);           //  8 MB [4096][1024]
  unsigned short* Wattn_t  = (unsigned short*)(ws + 8388608);     //  6 MB [3072][1024]
  unsigned short* Wproj_t  = (unsigned short*)(ws + 14680064);    //  2 MB [1024][1024]
  unsigned short* qkv      = (unsigned short*)(ws + 16777216);    // 24 MB [4096][3072]
  unsigned short* attn_out = (unsigned short*)(ws + 41943040);    //  8 MB [4096][1024]

  convert_f32_bf16<<<2048, 256, 0, stream>>>(x, x_bf, 4194304);
  transpose_f32_bf16<<<dim3(96, 32), dim3(32, 8), 0, stream>>>(W_attn, Wattn_t, 1024, 3072);
  transpose_f32_bf16<<<dim3(32, 32), dim3(32, 8), 0, stream>>>(W_proj, Wproj_t, 1024, 1024);

  gemm_bt<true><<<dim3(32, 24), 256, 0, stream>>>(x_bf, Wattn_t, b_attn, qkv, 4096, 3072, 1024);
  attn_kernel<<<1024, 256, 0, stream>>>(qkv, attn_out);
  gemm_bt<false><<<dim3(32, 8), 256, 0, stream>>>(attn_out, Wproj_t, b_proj, out, 4096, 1024, 1024);
}